// Round 1
// baseline (188.917 us; speedup 1.0000x reference)
//
#include <hip/hip_runtime.h>

// BackwardRPM: 16384 independent solves, 200 steps of
//   u <- clip(u - LR * (R^T (R (tanh(u W1 + b1) W2 + b2 - spec)))[:6])
// Algebra: fold R out. Qs = -LR * W2 R^T R[:, :6]  (64x6),
//          Ss = -LR * R[:, :6]^T R (6x40), es = Ss (b2 - spec) per sample.
// Step: t = u W1 + b1; h = tanh(t); u = clip(u + h Qs + es).

static constexpr float LR_ = 0.01f;

// ---------------- setup: compute Qs (64x6), Ss (6x40), Sb (6) into ws ------
// ws layout (floats): [0..383] Qs[i*6+j], [384..623] Ss[j*40+k], [624..629] Sb
__global__ void setup_k(const float* __restrict__ W2, const float* __restrict__ b2,
                        const float* __restrict__ R, float* __restrict__ ws)
{
    __shared__ float sSs[240];
    int t = threadIdx.x;
    if (t < 64) {
        // M[p] = sum_k W2[t,k] R[p,k];  Qs[t,j] = -LR * sum_p M[p] R[p,j]
        float M[8];
        #pragma unroll
        for (int p = 0; p < 8; ++p) {
            float acc = 0.f;
            for (int k = 0; k < 40; ++k) acc = fmaf(W2[t*40+k], R[p*40+k], acc);
            M[p] = acc;
        }
        #pragma unroll
        for (int j = 0; j < 6; ++j) {
            float acc = 0.f;
            #pragma unroll
            for (int p = 0; p < 8; ++p) acc = fmaf(M[p], R[p*40+j], acc);
            ws[t*6+j] = -LR_ * acc;
        }
    } else if (t < 304) {
        int idx = t - 64;
        int j = idx / 40, k = idx % 40;
        float acc = 0.f;
        #pragma unroll
        for (int p = 0; p < 8; ++p) acc = fmaf(R[p*40+j], R[p*40+k], acc);
        float v = -LR_ * acc;
        sSs[idx] = v;
        ws[384+idx] = v;
    }
    __syncthreads();
    if (t < 6) {
        float acc = 0.f;
        for (int k = 0; k < 40; ++k) acc = fmaf(sSs[t*40+k], b2[k], acc);
        ws[624+t] = acc;
    }
}

// ---------------- quad (4-lane) reductions via DPP quad_perm ---------------
__device__ __forceinline__ float qxor1(float x) {
    int r = __builtin_amdgcn_mov_dpp(__float_as_int(x), 0xB1, 0xF, 0xF, true); // [1,0,3,2]
    return __int_as_float(r);
}
__device__ __forceinline__ float qxor2(float x) {
    int r = __builtin_amdgcn_mov_dpp(__float_as_int(x), 0x4E, 0xF, 0xF, true); // [2,3,0,1]
    return __int_as_float(r);
}

// ---------------- main solver: 4 threads per sample, 16 hidden units each --
__global__ __launch_bounds__(256, 1) void solve_k(
    const float* __restrict__ spec, const float* __restrict__ W1,
    const float* __restrict__ b1, const float* __restrict__ ws,
    float* __restrict__ out, int batch)
{
    int tid = blockIdx.x * blockDim.x + threadIdx.x;
    int s   = tid >> 2;   // sample
    int sub = tid & 3;    // quarter of hidden dim
    if (s >= batch) return;

    const float* Qs = ws;
    const float* Ss = ws + 384;
    const float* Sb = ws + 624;

    const int ib = sub * 16;
    float w1r[6][16], b1r[16], qsr[16][6];
    #pragma unroll
    for (int j = 0; j < 6; ++j)
        #pragma unroll
        for (int i = 0; i < 16; ++i)
            w1r[j][i] = W1[j*64 + ib + i];          // W1 is (6,64) row-major
    #pragma unroll
    for (int i = 0; i < 16; ++i) b1r[i] = b1[ib + i];
    #pragma unroll
    for (int i = 0; i < 16; ++i)
        #pragma unroll
        for (int j = 0; j < 6; ++j)
            qsr[i][j] = Qs[(ib + i)*6 + j];

    // per-sample constant: es = Sb - Ss @ spec   (already includes -LR)
    float es[6];
    #pragma unroll
    for (int j = 0; j < 6; ++j) es[j] = Sb[j];
    const float* sp = spec + s * 40;
    for (int k = 0; k < 40; ++k) {
        float sv = sp[k];
        #pragma unroll
        for (int j = 0; j < 6; ++j) es[j] = fmaf(-sv, Ss[j*40+k], es[j]);
    }

    float u[6];
    #pragma unroll
    for (int j = 0; j < 6; ++j) u[j] = 0.5f;

    const float K = 2.8853900817779268f;  // 2*log2(e): exp2(K*t) = e^(2t)

    for (int step = 0; step < 200; ++step) {
        float h[16];
        #pragma unroll
        for (int i = 0; i < 16; ++i) {
            float t = b1r[i];
            #pragma unroll
            for (int j = 0; j < 6; ++j) t = fmaf(u[j], w1r[j][i], t);
            float E = __builtin_amdgcn_exp2f(t * K);           // e^(2t)
            h[i] = fmaf(-2.0f, __builtin_amdgcn_rcpf(E + 1.0f), 1.0f);  // tanh(t)
        }
        float g[6];
        #pragma unroll
        for (int j = 0; j < 6; ++j) g[j] = 0.f;
        #pragma unroll
        for (int i = 0; i < 16; ++i)
            #pragma unroll
            for (int j = 0; j < 6; ++j)
                g[j] = fmaf(h[i], qsr[i][j], g[j]);
        // reduce partial gradients across the 4 lanes of this sample's quad
        #pragma unroll
        for (int j = 0; j < 6; ++j) {
            g[j] += qxor1(g[j]);
            g[j] += qxor2(g[j]);
            u[j] = fminf(fmaxf(u[j] + g[j] + es[j], 0.f), 1.f);
        }
    }

    if (sub == 0) {
        float* o = out + s * 6;
        #pragma unroll
        for (int j = 0; j < 6; ++j) o[j] = u[j];
    }
}

extern "C" void kernel_launch(void* const* d_in, const int* in_sizes, int n_in,
                              void* d_out, int out_size, void* d_ws, size_t ws_size,
                              hipStream_t stream)
{
    const float* spec = (const float*)d_in[0];  // (B,40)
    const float* W1   = (const float*)d_in[1];  // (6,64)
    const float* b1   = (const float*)d_in[2];  // (64,)
    const float* W2   = (const float*)d_in[3];  // (64,40)
    const float* b2   = (const float*)d_in[4];  // (40,)
    const float* R    = (const float*)d_in[5];  // (8,40)
    float* ws = (float*)d_ws;
    int batch = in_sizes[0] / 40;

    hipLaunchKernelGGL(setup_k, dim3(1), dim3(320), 0, stream, W2, b2, R, ws);

    int threads = batch * 4;
    int blocks  = (threads + 255) / 256;
    hipLaunchKernelGGL(solve_k, dim3(blocks), dim3(256), 0, stream,
                       spec, W1, b1, ws, (float*)d_out, batch);
}

// Round 2
// 184.729 us; speedup vs baseline: 1.0227x; 1.0227x over previous
//
#include <hip/hip_runtime.h>

// BackwardRPM: 16384 independent solves, 200 steps of
//   u <- clip(u - LR * (R^T (R (tanh(u W1 + b1) W2 + b2 - spec)))[:6])
// Algebra: fold R out. Qs = -LR * W2 R^T R[:, :6]  (64x6),
//          Ss = -LR * R[:, :6]^T R (6x40), es = Ss (b2 - spec) per sample.
// Step: t = u W1 + b1; h = tanh(t); u = clip(u + h Qs + es).
//
// R2: 8 threads/sample (8 hidden units each) -> ~110 resident floats/thread,
// fits VGPRs without load-remat; 2048 waves = 2 waves/SIMD for latency hiding.
// Setup merged into solver prologue (per-block Qs/Ss in LDS). u and es folded
// into the reduction tree as (u+es)/8 per lane; clamp = med3.

static constexpr float LR_ = 0.01f;

__device__ __forceinline__ float qxor1(float x) {
    int r = __builtin_amdgcn_mov_dpp(__float_as_int(x), 0xB1, 0xF, 0xF, true); // quad_perm [1,0,3,2]
    return __int_as_float(r);
}
__device__ __forceinline__ float qxor2(float x) {
    int r = __builtin_amdgcn_mov_dpp(__float_as_int(x), 0x4E, 0xF, 0xF, true); // quad_perm [2,3,0,1]
    return __int_as_float(r);
}
__device__ __forceinline__ float sxor4(float x) {
    // ds_swizzle BitMode: offset = (xor<<10)|(or<<5)|and = (4<<10)|0x1F = 0x101F
    int r = __builtin_amdgcn_ds_swizzle(__float_as_int(x), 0x101F);
    return __int_as_float(r);
}

__global__ __launch_bounds__(256, 2) void solve_k(
    const float* __restrict__ spec, const float* __restrict__ W1,
    const float* __restrict__ b1,   const float* __restrict__ W2,
    const float* __restrict__ b2,   const float* __restrict__ R,
    float* __restrict__ out, int batch)
{
    __shared__ float sQs[384];   // Qs[i][j] = sQs[i*6+j], i<64, j<6 (includes -LR)
    __shared__ float sSs[240];   // Ss[j][k] = sSs[j*40+k], j<6, k<40 (includes -LR)

    const int t = threadIdx.x;

    // ---- per-block setup: Qs = -LR * W2 R^T R6, Ss = -LR * R6^T R ----
    if (t < 64) {
        float M[8];
        #pragma unroll
        for (int p = 0; p < 8; ++p) {
            float acc = 0.f;
            for (int k = 0; k < 40; ++k) acc = fmaf(W2[t*40+k], R[p*40+k], acc);
            M[p] = acc;
        }
        #pragma unroll
        for (int j = 0; j < 6; ++j) {
            float acc = 0.f;
            #pragma unroll
            for (int p = 0; p < 8; ++p) acc = fmaf(M[p], R[p*40+j], acc);
            sQs[t*6+j] = -LR_ * acc;
        }
    } else {
        for (int idx = t - 64; idx < 240; idx += 192) {
            int j = idx / 40, k = idx % 40;
            float acc = 0.f;
            #pragma unroll
            for (int p = 0; p < 8; ++p) acc = fmaf(R[p*40+j], R[p*40+k], acc);
            sSs[idx] = -LR_ * acc;
        }
    }
    __syncthreads();

    // ---- per-thread constants ----
    const int tid = blockIdx.x * 256 + t;
    const int s   = tid >> 3;    // sample
    const int sub = tid & 7;     // eighth of hidden dim
    const int ib  = sub * 8;
    const bool live = (s < batch);
    const int sl = live ? s : 0;

    float w1r[6][8], b1r[8], qsr[8][6];
    #pragma unroll
    for (int j = 0; j < 6; ++j)
        #pragma unroll
        for (int i = 0; i < 8; ++i)
            w1r[j][i] = W1[j*64 + ib + i];          // W1 is (6,64) row-major
    #pragma unroll
    for (int i = 0; i < 8; ++i) b1r[i] = b1[ib + i];
    #pragma unroll
    for (int i = 0; i < 8; ++i)
        #pragma unroll
        for (int j = 0; j < 6; ++j)
            qsr[i][j] = sQs[(ib + i)*6 + j];

    // es[j] = sum_k Ss[j][k] * (b2[k] - spec[k]);  esd = es/8 (fold into tree)
    float esd[6];
    #pragma unroll
    for (int j = 0; j < 6; ++j) esd[j] = 0.f;
    const float* sp = spec + sl * 40;
    for (int k = 0; k < 40; ++k) {
        float v = b2[k] - sp[k];
        #pragma unroll
        for (int j = 0; j < 6; ++j) esd[j] = fmaf(v, sSs[j*40+k], esd[j]);
    }
    #pragma unroll
    for (int j = 0; j < 6; ++j) esd[j] *= 0.125f;

    float u[6];
    #pragma unroll
    for (int j = 0; j < 6; ++j) u[j] = 0.5f;

    const float K = 2.8853900817779268f;  // 2*log2(e): exp2(K*t) = e^(2t)

    for (int step = 0; step < 200; ++step) {
        float h[8];
        #pragma unroll
        for (int i = 0; i < 8; ++i) {
            float tt = b1r[i];
            #pragma unroll
            for (int j = 0; j < 6; ++j) tt = fmaf(u[j], w1r[j][i], tt);
            float E = __builtin_amdgcn_exp2f(tt * K);                       // e^(2t)
            h[i] = fmaf(-2.0f, __builtin_amdgcn_rcpf(E + 1.0f), 1.0f);     // tanh(t)
        }
        // per-lane partial: g = (u + es)/8 + sum_i h[i] * Qs[i][:]
        float g[6];
        #pragma unroll
        for (int j = 0; j < 6; ++j) g[j] = fmaf(u[j], 0.125f, esd[j]);
        #pragma unroll
        for (int i = 0; i < 8; ++i)
            #pragma unroll
            for (int j = 0; j < 6; ++j)
                g[j] = fmaf(h[i], qsr[i][j], g[j]);
        // allreduce over the 8 lanes of this sample (xor4 first to hide LDS-pipe latency)
        #pragma unroll
        for (int j = 0; j < 6; ++j) g[j] += sxor4(g[j]);
        #pragma unroll
        for (int j = 0; j < 6; ++j) {
            g[j] += qxor1(g[j]);
            g[j] += qxor2(g[j]);
            u[j] = fminf(fmaxf(g[j], 0.f), 1.f);
        }
    }

    if (live && sub == 0) {
        float* o = out + s * 6;
        #pragma unroll
        for (int j = 0; j < 6; ++j) o[j] = u[j];
    }
}

extern "C" void kernel_launch(void* const* d_in, const int* in_sizes, int n_in,
                              void* d_out, int out_size, void* d_ws, size_t ws_size,
                              hipStream_t stream)
{
    const float* spec = (const float*)d_in[0];  // (B,40)
    const float* W1   = (const float*)d_in[1];  // (6,64)
    const float* b1   = (const float*)d_in[2];  // (64,)
    const float* W2   = (const float*)d_in[3];  // (64,40)
    const float* b2   = (const float*)d_in[4];  // (40,)
    const float* R    = (const float*)d_in[5];  // (8,40)
    int batch = in_sizes[0] / 40;

    int threads = batch * 8;
    int blocks  = (threads + 255) / 256;
    hipLaunchKernelGGL(solve_k, dim3(blocks), dim3(256), 0, stream,
                       spec, W1, b1, W2, b2, R, (float*)d_out, batch);
}